// Round 1
// baseline (2740.068 us; speedup 1.0000x reference)
//
#include <hip/hip_runtime.h>
#include <math.h>

#define BB 16
#define TT 2048
#define DD 1024
#define HH 64

// ---------------------------------------------------------------------------
// Kernel 1: QKV projection. One block per row of x (B*T rows).
// Stage x-row (1024 f32 = 4 KB) in LDS; threads 0..191 each compute one
// output column dot (64 cols x {Wq,Wk,Wv}).
// ---------------------------------------------------------------------------
__global__ __launch_bounds__(256) void qkv_proj(
    const float* __restrict__ x,
    const float* __restrict__ Wq,
    const float* __restrict__ Wk,
    const float* __restrict__ Wv,
    float* __restrict__ q, float* __restrict__ k, float* __restrict__ v) {
  __shared__ float xs[DD];
  const int row = blockIdx.x;  // 0 .. B*T-1
  const float* xr = x + (size_t)row * DD;
  for (int i = threadIdx.x; i < DD; i += 256) xs[i] = xr[i];
  __syncthreads();
  const int j = threadIdx.x;
  if (j < 192) {
    const int m = j >> 6;    // 0:q 1:k 2:v
    const int h = j & 63;
    const float* W = (m == 0) ? Wq : (m == 1) ? Wk : Wv;
    float acc = 0.f;
#pragma unroll 8
    for (int d = 0; d < DD; ++d) acc += xs[d] * W[d * HH + h];
    float* outp = (m == 0) ? q : (m == 1) ? k : v;
    outp[(size_t)row * HH + h] = acc;
  }
}

// ---------------------------------------------------------------------------
// Kernel 2: causal attention, one wave (64 threads) per (b, t) query row.
// Online softmax over 64-key chunks staged in LDS.
//   phase A: lane = key index   -> score = q . K[s]
//   phase B: lane = head dim h  -> acc[h] += sum_s p[s] * V[s][h]
// LDS K/V tiles padded to stride 65 to avoid 32-way bank conflicts in the
// per-lane row dot.
// ---------------------------------------------------------------------------
__global__ __launch_bounds__(64) void attn_causal(
    const float* __restrict__ q,
    const float* __restrict__ k,
    const float* __restrict__ v,
    float* __restrict__ out) {
  const int t = blockIdx.x;
  const int b = blockIdx.y;
  const int lane = threadIdx.x;

  __shared__ float qs[HH];
  __shared__ float ks[64][HH + 1];
  __shared__ float vs[64][HH + 1];
  __shared__ float ps[64];

  const size_t brow = (size_t)b * TT;
  qs[lane] = q[(brow + t) * HH + lane];

  float m_run = -INFINITY;
  float l_run = 0.f;
  float acc = 0.f;

  const int nchunk = (t >> 6) + 1;
  for (int c = 0; c < nchunk; ++c) {
    const int s0 = c << 6;
    const float* kb = k + (brow + s0) * HH;
    const float* vb = v + (brow + s0) * HH;
    __syncthreads();  // protect ks/vs/ps from previous iteration's readers
#pragma unroll 4
    for (int s = 0; s < 64; ++s) {
      ks[s][lane] = kb[s * HH + lane];
      vs[s][lane] = vb[s * HH + lane];
    }
    __syncthreads();

    const int skey = s0 + lane;
    float score;
    if (skey <= t) {
      float d = 0.f;
#pragma unroll 8
      for (int h = 0; h < HH; ++h) d += qs[h] * ks[lane][h];
      score = d * 0.125f;  // 1/sqrt(64)
    } else {
      score = -INFINITY;
    }

    // wave-wide max over 64 lanes
    float mx = score;
#pragma unroll
    for (int off = 32; off; off >>= 1) mx = fmaxf(mx, __shfl_xor(mx, off));
    const float m_new = fmaxf(m_run, mx);

    const float p = (skey <= t) ? __expf(score - m_new) : 0.f;
    float psum = p;
#pragma unroll
    for (int off = 32; off; off >>= 1) psum += __shfl_xor(psum, off);

    const float corr = (m_run == -INFINITY) ? 0.f : __expf(m_run - m_new);
    l_run = l_run * corr + psum;
    acc *= corr;
    ps[lane] = p;
    __syncthreads();

#pragma unroll 8
    for (int s = 0; s < 64; ++s) acc += ps[s] * vs[s][lane];
    m_run = m_new;
  }

  out[(brow + t) * HH + lane] = acc / l_run;
}

extern "C" void kernel_launch(void* const* d_in, const int* in_sizes, int n_in,
                              void* d_out, int out_size, void* d_ws, size_t ws_size,
                              hipStream_t stream) {
  const float* x  = (const float*)d_in[0];
  const float* Wq = (const float*)d_in[1];
  const float* Wk = (const float*)d_in[2];
  const float* Wv = (const float*)d_in[3];
  float* out = (float*)d_out;

  const size_t bth = (size_t)BB * TT * HH;  // 2,097,152 floats
  float* q = (float*)d_ws;
  float* k = q + bth;
  float* v = k + bth;

  qkv_proj<<<BB * TT, 256, 0, stream>>>(x, Wq, Wk, Wv, q, k, v);

  dim3 grid(TT, BB);
  attn_causal<<<grid, 64, 0, stream>>>(q, k, v, out);
}

// Round 2
// 808.275 us; speedup vs baseline: 3.3900x; 3.3900x over previous
//
#include <hip/hip_runtime.h>
#include <math.h>

#define BB 16
#define TT 2048
#define DD 1024
#define HH 64
#define QTILES (TT / 64)
#define RB 8

// ---------------------------------------------------------------------------
// Kernel 1: QKV projection. 8 x-rows per 192-thread block (3 waves: one per
// matrix, lane = output column). W element loaded once per block, reused 8x
// -> L2 W-traffic 3.1 GB instead of 25 GB. xs reads are wave-broadcast.
// ---------------------------------------------------------------------------
__global__ __launch_bounds__(192) void qkv_proj(
    const float* __restrict__ x,
    const float* __restrict__ Wq,
    const float* __restrict__ Wk,
    const float* __restrict__ Wv,
    float* __restrict__ qo, float* __restrict__ ko, float* __restrict__ vo) {
  __shared__ float xs[RB][DD];  // 32 KB
  const size_t r0 = (size_t)blockIdx.x * RB;
  const float4* src = (const float4*)(x + r0 * DD);
  float4* dst = (float4*)&xs[0][0];
  for (int i = threadIdx.x; i < RB * DD / 4; i += 192) dst[i] = src[i];
  __syncthreads();

  const int mtx = threadIdx.x >> 6;  // wave 0:q 1:k 2:v
  const int h = threadIdx.x & 63;
  const float* W = (mtx == 0) ? Wq : (mtx == 1) ? Wk : Wv;
  float* outp = (mtx == 0) ? qo : (mtx == 1) ? ko : vo;

  float acc[RB];
#pragma unroll
  for (int r = 0; r < RB; ++r) acc[r] = 0.f;

#pragma unroll 4
  for (int d = 0; d < DD; ++d) {
    float wv = W[d * HH + h];  // coalesced across lanes, L2-resident
#pragma unroll
    for (int r = 0; r < RB; ++r) acc[r] = fmaf(xs[r][d], wv, acc[r]);
  }
#pragma unroll
  for (int r = 0; r < RB; ++r) outp[(r0 + r) * HH + h] = acc[r];
}

// ---------------------------------------------------------------------------
// Kernel 2: flash attention. One 512-thread block (8 waves) per 64-query
// tile; each wave owns 8 queries. Per 64-key chunk: stage K transposed
// (stride 65, 2-way bank alias = free) + V row-major once, amortized over 64
// queries. Score phase: lane = key, 1 kst read feeds 8 FMA. Softmax:
// wave-wide butterfly. PV: lane = h, 1 vs read feeds 8 FMA, p via LDS
// broadcast. fp32 throughout.
// ---------------------------------------------------------------------------
__global__ __launch_bounds__(512) void attn_flash(
    const float* __restrict__ q,
    const float* __restrict__ k,
    const float* __restrict__ v,
    float* __restrict__ out) {
  const int qt = (QTILES - 1) - blockIdx.x;  // big tiles dispatched first
  const int b = blockIdx.y;
  const int t0 = qt << 6;
  const int tid = threadIdx.x;
  const int lane = tid & 63;
  const int w = tid >> 6;    // 0..7
  const int Q0 = w << 3;     // 8 queries per wave

  __shared__ float qs[64][64];       // 16 KB, broadcast reads only
  __shared__ float kst[64][65];      // 16.25 KB, K transposed [h][s]
  __shared__ float vs[64][64];       // 16 KB
  __shared__ float ps[8][8][64];     // 16 KB, per-wave p rows

  const size_t brow = (size_t)b * TT;
  {
    const float4* src = (const float4*)(q + (brow + t0) * HH);
    float4* dst = (float4*)&qs[0][0];
#pragma unroll
    for (int i = tid; i < 1024; i += 512) dst[i] = src[i];
  }

  float m[8], l[8], acc[8];
#pragma unroll
  for (int i = 0; i < 8; ++i) { m[i] = -INFINITY; l[i] = 0.f; acc[i] = 0.f; }

  const int nchunk = qt + 1;
  for (int c = 0; c < nchunk; ++c) {
    const int s0 = c << 6;
    __syncthreads();  // previous chunk's readers done (also covers qs load)
    const float4* kb = (const float4*)(k + (brow + s0) * HH);
    const float4* vb = (const float4*)(v + (brow + s0) * HH);
#pragma unroll
    for (int f = tid; f < 1024; f += 512) {
      float4 kv = kb[f];
      const int s = f >> 4;
      const int h0 = (f & 15) << 2;
      kst[h0][s] = kv.x;
      kst[h0 + 1][s] = kv.y;
      kst[h0 + 2][s] = kv.z;
      kst[h0 + 3][s] = kv.w;
      ((float4*)&vs[0][0])[f] = vb[f];
    }
    __syncthreads();

    // ---- scores: lane = key s0+lane ----
    float sc[8];
#pragma unroll
    for (int i = 0; i < 8; ++i) sc[i] = 0.f;
#pragma unroll 8
    for (int h = 0; h < 64; ++h) {
      const float kv = kst[h][lane];
#pragma unroll
      for (int i = 0; i < 8; ++i) sc[i] = fmaf(qs[Q0 + i][h], kv, sc[i]);
    }

    const bool diag = (c == qt);
#pragma unroll
    for (int i = 0; i < 8; ++i) {
      float s_ = sc[i] * 0.125f;  // 1/sqrt(64)
      if (diag && (s0 + lane > t0 + Q0 + i)) s_ = -INFINITY;
      float mx = s_;
#pragma unroll
      for (int off = 32; off; off >>= 1) mx = fmaxf(mx, __shfl_xor(mx, off));
      const float mnew = fmaxf(m[i], mx);
      const float p = __expf(s_ - mnew);  // exp(-inf)=0 handles mask
      float psum = p;
#pragma unroll
      for (int off = 32; off; off >>= 1) psum += __shfl_xor(psum, off);
      const float corr = __expf(m[i] - mnew);  // exp(-inf)=0 first chunk
      l[i] = l[i] * corr + psum;
      acc[i] *= corr;
      m[i] = mnew;
      ps[w][i][lane] = p;
    }

    // ---- PV: lane = head dim ----
#pragma unroll 8
    for (int s = 0; s < 64; ++s) {
      const float vv = vs[s][lane];
#pragma unroll
      for (int i = 0; i < 8; ++i) acc[i] = fmaf(ps[w][i][s], vv, acc[i]);
    }
  }

#pragma unroll
  for (int i = 0; i < 8; ++i)
    out[(brow + t0 + Q0 + i) * HH + lane] = acc[i] / l[i];
}

extern "C" void kernel_launch(void* const* d_in, const int* in_sizes, int n_in,
                              void* d_out, int out_size, void* d_ws, size_t ws_size,
                              hipStream_t stream) {
  const float* x  = (const float*)d_in[0];
  const float* Wq = (const float*)d_in[1];
  const float* Wk = (const float*)d_in[2];
  const float* Wv = (const float*)d_in[3];
  float* out = (float*)d_out;

  const size_t bth = (size_t)BB * TT * HH;
  float* q = (float*)d_ws;
  float* k = q + bth;
  float* v = k + bth;

  qkv_proj<<<(BB * TT) / RB, 192, 0, stream>>>(x, Wq, Wk, Wv, q, k, v);

  dim3 grid(QTILES, BB);
  attn_flash<<<grid, 512, 0, stream>>>(q, k, v, out);
}

// Round 3
// 130.656 us; speedup vs baseline: 20.9716x; 6.1863x over previous
//
#include <hip/hip_runtime.h>
#include <math.h>

#define BB 16
#define TT 2048
#define DD 1024
#define HH 64
#define QTILES (TT / 64)

typedef short bf16x8 __attribute__((ext_vector_type(8)));
typedef float f32x4 __attribute__((ext_vector_type(4)));

__device__ __forceinline__ short f2bf(float f) {
  union { float f; unsigned u; } c; c.f = f;
  unsigned u = c.u + 0x7FFFu + ((c.u >> 16) & 1u);  // RNE
  return (short)(u >> 16);
}

// [64][64] bf16 tile, row stride 128 B; XOR-swizzle 16B units by (row&7).
// Makes "16 lanes read 16 different rows at same col" conflict-free (T2).
__device__ __forceinline__ void* lds_swz(void* base, int row, int col) {
  int byte = (row << 7) + (col << 1);
  byte ^= (row & 7) << 4;
  return (void*)((char*)base + byte);
}

// ---------------------------------------------------------------------------
// Pack Wq|Wk|Wv (fp32 [D][H]) -> Wt bf16 [192][1024]  (n-major, k contiguous)
// ---------------------------------------------------------------------------
__global__ __launch_bounds__(256) void pack_wt(
    const float* __restrict__ Wq, const float* __restrict__ Wk,
    const float* __restrict__ Wv, short* __restrict__ wt) {
  const int idx = blockIdx.x * 256 + threadIdx.x;  // 0..24575
  const int n = idx >> 7;                          // 0..191
  const int k0 = (idx & 127) << 3;                 // 0..1016
  const float* W = (n < 64) ? Wq : (n < 128) ? Wk : Wv;
  const int h = n & 63;
  bf16x8 o;
#pragma unroll
  for (int j = 0; j < 8; ++j) o[j] = f2bf(W[(k0 + j) * HH + h]);
  *(bf16x8*)&wt[n * DD + k0] = o;
}

// ---------------------------------------------------------------------------
// QKV GEMM: [32768 x 1024] @ [1024 x 192] in bf16 MFMA, out q/k/v bf16.
// 256 thr = 4 waves; each wave: 64 rows x 48 cols (4 m-frags x 3 n-frags).
// A (x tile) staged fp32->bf16 to swizzled LDS; B from Wt global (L2).
// ---------------------------------------------------------------------------
__global__ __launch_bounds__(256) void qkv_mfma(
    const float* __restrict__ x, const short* __restrict__ wt,
    short* __restrict__ qo, short* __restrict__ ko, short* __restrict__ vo) {
  __shared__ short xs[64 * 64];  // 8 KB
  const int tid = threadIdx.x;
  const int lane = tid & 63;
  const int w = tid >> 6;
  const int q16 = lane & 15;
  const int g = lane >> 4;
  const size_t r0 = (size_t)blockIdx.x * 64;

  const int srow = tid >> 2;          // staging row 0..63
  const int sc = (tid & 3) << 4;      // 0,16,32,48
  const float* xrow = x + (r0 + srow) * DD + sc;

  f32x4 acc[4][3];
#pragma unroll
  for (int mf = 0; mf < 4; ++mf)
#pragma unroll
    for (int nf = 0; nf < 3; ++nf) acc[mf][nf] = (f32x4){0.f, 0.f, 0.f, 0.f};

  for (int ks = 0; ks < 16; ++ks) {
    const int k0 = ks << 6;
    __syncthreads();
    {
      const float4* xp = (const float4*)(xrow + k0);
      float4 f0 = xp[0], f1 = xp[1], f2 = xp[2], f3 = xp[3];
      bf16x8 s0, s1;
      s0[0] = f2bf(f0.x); s0[1] = f2bf(f0.y); s0[2] = f2bf(f0.z); s0[3] = f2bf(f0.w);
      s0[4] = f2bf(f1.x); s0[5] = f2bf(f1.y); s0[6] = f2bf(f1.z); s0[7] = f2bf(f1.w);
      s1[0] = f2bf(f2.x); s1[1] = f2bf(f2.y); s1[2] = f2bf(f2.z); s1[3] = f2bf(f2.w);
      s1[4] = f2bf(f3.x); s1[5] = f2bf(f3.y); s1[6] = f2bf(f3.z); s1[7] = f2bf(f3.w);
      *(bf16x8*)lds_swz(xs, srow, sc) = s0;
      *(bf16x8*)lds_swz(xs, srow, sc + 8) = s1;
    }
    __syncthreads();

    bf16x8 bfr[3][2];
#pragma unroll
    for (int nf = 0; nf < 3; ++nf) {
      const int n = w * 48 + nf * 16 + q16;
#pragma unroll
      for (int kf = 0; kf < 2; ++kf)
        bfr[nf][kf] = *(const bf16x8*)&wt[n * DD + k0 + kf * 32 + g * 8];
    }
    bf16x8 afr[4][2];
#pragma unroll
    for (int mf = 0; mf < 4; ++mf)
#pragma unroll
      for (int kf = 0; kf < 2; ++kf)
        afr[mf][kf] = *(bf16x8*)lds_swz(xs, mf * 16 + q16, kf * 32 + g * 8);

#pragma unroll
    for (int mf = 0; mf < 4; ++mf)
#pragma unroll
      for (int nf = 0; nf < 3; ++nf)
#pragma unroll
        for (int kf = 0; kf < 2; ++kf)
          acc[mf][nf] = __builtin_amdgcn_mfma_f32_16x16x32_bf16(
              afr[mf][kf], bfr[nf][kf], acc[mf][nf], 0, 0, 0);
  }

#pragma unroll
  for (int nf = 0; nf < 3; ++nf) {
    const int n = w * 48 + nf * 16 + q16;
    const int mat = n >> 6;
    const int h = n & 63;
    short* outp = (mat == 0) ? qo : (mat == 1) ? ko : vo;
#pragma unroll
    for (int mf = 0; mf < 4; ++mf)
#pragma unroll
      for (int r = 0; r < 4; ++r)
        outp[(r0 + mf * 16 + g * 4 + r) * HH + h] = f2bf(acc[mf][nf][r]);
  }
}

// ---------------------------------------------------------------------------
// V transpose: v bf16 [b][t][h] -> vt bf16 [b][h][t]
// ---------------------------------------------------------------------------
__global__ __launch_bounds__(256) void transpose_v(
    const short* __restrict__ v, short* __restrict__ vt) {
  const int idx = blockIdx.x * 256 + threadIdx.x;  // 0..262143
  const int b = idx >> 14;
  const int r = idx & 16383;
  const int h = r >> 8;
  const int t0 = (r & 255) << 3;
  bf16x8 o;
#pragma unroll
  for (int j = 0; j < 8; ++j) o[j] = v[((size_t)b * TT + t0 + j) * HH + h];
  *(bf16x8*)&vt[((size_t)b * HH + h) * TT + t0] = o;
}

// ---------------------------------------------------------------------------
// Flash attention, bf16 MFMA. 256 thr = 4 waves; block = 64-query tile,
// wave owns 16 q-rows. Per 64-key chunk: S = Q.K^T (8 mfma), online softmax
// on C-layout frags, P bounced through pad-72 LDS to A-layout, O += P.V
// (8 mfma, V^T tile swizzled). fp32 accumulators and output.
// ---------------------------------------------------------------------------
__global__ __launch_bounds__(256) void attn_mfma(
    const short* __restrict__ q, const short* __restrict__ k,
    const short* __restrict__ vt, float* __restrict__ out) {
  __shared__ short klds[64 * 64];     // 8 KB (also used to stage Q once)
  __shared__ short vlds[64 * 64];     // 8 KB
  __shared__ short ps[4][16 * 72];    // 9 KB, per-wave P tile [16q][72]

  const int qt = (QTILES - 1) - blockIdx.x;
  const int b = blockIdx.y;
  const int t0 = qt << 6;
  const int tid = threadIdx.x;
  const int lane = tid & 63;
  const int w = tid >> 6;
  const int q16 = lane & 15;
  const int g = lane >> 4;

  const size_t brow = (size_t)b * TT;
  const short* qg = q + (brow + t0) * HH;
  const short* kg = k + brow * HH;
  const short* vtg = vt + (size_t)b * HH * TT;

  const int srow = tid >> 2;      // 0..63
  const int sc = (tid & 3) << 4;  // 0,16,32,48

  // stage Q once (into klds), pull per-wave A-frags to registers
  *(bf16x8*)lds_swz(klds, srow, sc) = *(const bf16x8*)&qg[srow * HH + sc];
  *(bf16x8*)lds_swz(klds, srow, sc + 8) = *(const bf16x8*)&qg[srow * HH + sc + 8];
  __syncthreads();
  bf16x8 qa[2];
#pragma unroll
  for (int kf = 0; kf < 2; ++kf)
    qa[kf] = *(bf16x8*)lds_swz(klds, w * 16 + q16, kf * 32 + g * 8);

  f32x4 po[4];
  float m[4], l[4];
#pragma unroll
  for (int nf = 0; nf < 4; ++nf) po[nf] = (f32x4){0.f, 0.f, 0.f, 0.f};
#pragma unroll
  for (int r = 0; r < 4; ++r) { m[r] = -INFINITY; l[r] = 0.f; }

  const int qrow = t0 + w * 16 + g * 4;  // + r

  for (int c = 0; c <= qt; ++c) {
    const int s0 = c << 6;
    __syncthreads();  // previous chunk's readers done
    *(bf16x8*)lds_swz(klds, srow, sc) = *(const bf16x8*)&kg[(s0 + srow) * HH + sc];
    *(bf16x8*)lds_swz(klds, srow, sc + 8) = *(const bf16x8*)&kg[(s0 + srow) * HH + sc + 8];
    *(bf16x8*)lds_swz(vlds, srow, sc) = *(const bf16x8*)&vtg[srow * TT + s0 + sc];
    *(bf16x8*)lds_swz(vlds, srow, sc + 8) = *(const bf16x8*)&vtg[srow * TT + s0 + sc + 8];
    __syncthreads();

    // ---- S = Q . K^T ----
    f32x4 sfr[4];
#pragma unroll
    for (int nf = 0; nf < 4; ++nf) sfr[nf] = (f32x4){0.f, 0.f, 0.f, 0.f};
#pragma unroll
    for (int nf = 0; nf < 4; ++nf)
#pragma unroll
      for (int kf = 0; kf < 2; ++kf) {
        bf16x8 kb = *(bf16x8*)lds_swz(klds, nf * 16 + q16, kf * 32 + g * 8);
        sfr[nf] = __builtin_amdgcn_mfma_f32_16x16x32_bf16(qa[kf], kb, sfr[nf], 0, 0, 0);
      }

    // ---- scale + causal mask (no-op for c<qt) ----
#pragma unroll
    for (int nf = 0; nf < 4; ++nf) {
      const int sg = s0 + nf * 16 + q16;
#pragma unroll
      for (int r = 0; r < 4; ++r) {
        float sv = sfr[nf][r] * 0.125f;
        sfr[nf][r] = (sg > qrow + r) ? -INFINITY : sv;
      }
    }

    // ---- online softmax (rows live in 16-lane groups) ----
    float mx[4], corr[4], psum[4];
#pragma unroll
    for (int r = 0; r < 4; ++r)
      mx[r] = fmaxf(fmaxf(sfr[0][r], sfr[1][r]), fmaxf(sfr[2][r], sfr[3][r]));
#pragma unroll
    for (int off = 8; off; off >>= 1)
#pragma unroll
      for (int r = 0; r < 4; ++r) mx[r] = fmaxf(mx[r], __shfl_xor(mx[r], off));
#pragma unroll
    for (int r = 0; r < 4; ++r) {
      const float mn = fmaxf(m[r], mx[r]);
      corr[r] = __expf(m[r] - mn);
      m[r] = mn;
    }
#pragma unroll
    for (int nf = 0; nf < 4; ++nf)
#pragma unroll
      for (int r = 0; r < 4; ++r) sfr[nf][r] = __expf(sfr[nf][r] - m[r]);
#pragma unroll
    for (int r = 0; r < 4; ++r)
      psum[r] = (sfr[0][r] + sfr[1][r]) + (sfr[2][r] + sfr[3][r]);
#pragma unroll
    for (int off = 8; off; off >>= 1)
#pragma unroll
      for (int r = 0; r < 4; ++r) psum[r] += __shfl_xor(psum[r], off);
#pragma unroll
    for (int r = 0; r < 4; ++r) l[r] = l[r] * corr[r] + psum[r];
#pragma unroll
    for (int nf = 0; nf < 4; ++nf)
#pragma unroll
      for (int r = 0; r < 4; ++r) po[nf][r] *= corr[r];

    // ---- P (C-layout) -> bf16 LDS tile [16q][72] (A-layout source) ----
#pragma unroll
    for (int nf = 0; nf < 4; ++nf)
#pragma unroll
      for (int r = 0; r < 4; ++r)
        ps[w][(g * 4 + r) * 72 + nf * 16 + q16] = f2bf(sfr[nf][r]);
    // same-wave write->read; compiler inserts lgkmcnt

    // ---- O += P . V ----
    bf16x8 pa[2];
#pragma unroll
    for (int kf = 0; kf < 2; ++kf)
      pa[kf] = *(const bf16x8*)&ps[w][q16 * 72 + kf * 32 + g * 8];
#pragma unroll
    for (int nf = 0; nf < 4; ++nf)
#pragma unroll
      for (int kf = 0; kf < 2; ++kf) {
        bf16x8 vb = *(bf16x8*)lds_swz(vlds, nf * 16 + q16, kf * 32 + g * 8);
        po[nf] = __builtin_amdgcn_mfma_f32_16x16x32_bf16(pa[kf], vb, po[nf], 0, 0, 0);
      }
  }

#pragma unroll
  for (int nf = 0; nf < 4; ++nf) {
    const int h = nf * 16 + q16;
#pragma unroll
    for (int r = 0; r < 4; ++r)
      out[(brow + qrow + r) * HH + h] = po[nf][r] / l[r];
  }
}

extern "C" void kernel_launch(void* const* d_in, const int* in_sizes, int n_in,
                              void* d_out, int out_size, void* d_ws, size_t ws_size,
                              hipStream_t stream) {
  const float* x  = (const float*)d_in[0];
  const float* Wq = (const float*)d_in[1];
  const float* Wk = (const float*)d_in[2];
  const float* Wv = (const float*)d_in[3];
  float* out = (float*)d_out;

  const size_t bth = (size_t)BB * TT * HH;  // 2,097,152
  short* qb  = (short*)d_ws;
  short* kb  = qb + bth;
  short* vb  = kb + bth;
  short* vtb = vb + bth;
  short* wtb = vtb + bth;  // 192*1024 bf16

  pack_wt<<<96, 256, 0, stream>>>(Wq, Wk, Wv, wtb);
  qkv_mfma<<<(BB * TT) / 64, 256, 0, stream>>>(x, wtb, qb, kb, vb);
  transpose_v<<<(BB * HH * TT / 8) / 256, 256, 0, stream>>>(vb, vtb);
  attn_mfma<<<dim3(QTILES, BB), 256, 0, stream>>>(qb, kb, vtb, out);
}

// Round 4
// 90.863 us; speedup vs baseline: 30.1559x; 1.4379x over previous
//
#include <hip/hip_runtime.h>
#include <math.h>

#define BB 16
#define TT 2048
#define DD 1024
#define HH 64

typedef short bf16x8 __attribute__((ext_vector_type(8)));
typedef short bf16x4 __attribute__((ext_vector_type(4)));
typedef float f32x4 __attribute__((ext_vector_type(4)));

__device__ __forceinline__ short f2bf(float f) {
  union { float f; unsigned u; } c; c.f = f;
  unsigned u = c.u + 0x7FFFu + ((c.u >> 16) & 1u);  // RNE
  return (short)(u >> 16);
}

// [64][64] bf16 tile, row stride 128 B; XOR-swizzle 16B units by (row&7).
__device__ __forceinline__ void* lds_swz(void* base, int row, int col) {
  int byte = (row << 7) + (col << 1);
  byte ^= (row & 7) << 4;
  return (void*)((char*)base + byte);
}

__device__ __forceinline__ void pack16(const float4& a0, const float4& a1,
                                       const float4& a2, const float4& a3,
                                       bf16x8& s0, bf16x8& s1) {
  s0[0] = f2bf(a0.x); s0[1] = f2bf(a0.y); s0[2] = f2bf(a0.z); s0[3] = f2bf(a0.w);
  s0[4] = f2bf(a1.x); s0[5] = f2bf(a1.y); s0[6] = f2bf(a1.z); s0[7] = f2bf(a1.w);
  s1[0] = f2bf(a2.x); s1[1] = f2bf(a2.y); s1[2] = f2bf(a2.z); s1[3] = f2bf(a2.w);
  s1[4] = f2bf(a3.x); s1[5] = f2bf(a3.y); s1[6] = f2bf(a3.z); s1[7] = f2bf(a3.w);
}

// ---------------------------------------------------------------------------
// Pack Wq|Wk|Wv (fp32 [D][H]) -> Wt bf16 [192][1024]  (n-major, k contiguous)
// ---------------------------------------------------------------------------
__global__ __launch_bounds__(256) void pack_wt(
    const float* __restrict__ Wq, const float* __restrict__ Wk,
    const float* __restrict__ Wv, short* __restrict__ wt) {
  const int idx = blockIdx.x * 256 + threadIdx.x;  // 0..24575
  const int n = idx >> 7;
  const int k0 = (idx & 127) << 3;
  const float* W = (n < 64) ? Wq : (n < 128) ? Wk : Wv;
  const int h = n & 63;
  bf16x8 o;
#pragma unroll
  for (int j = 0; j < 8; ++j) o[j] = f2bf(W[(k0 + j) * HH + h]);
  *(bf16x8*)&wt[n * DD + k0] = o;
}

// ---------------------------------------------------------------------------
// QKV GEMM, double-buffered: [32768 x 1024] @ [1024 x 192] bf16 MFMA.
// One barrier per k-step; next x-tile + next B-frags prefetched to regs and
// consumed after compute. V is written TRANSPOSED to vt [b][h][t].
// ---------------------------------------------------------------------------
__global__ __launch_bounds__(256) void qkv_mfma(
    const float* __restrict__ x, const short* __restrict__ wt,
    short* __restrict__ qo, short* __restrict__ ko, short* __restrict__ vt) {
  __shared__ short xs[2][64 * 64];  // 16 KB
  const int tid = threadIdx.x;
  const int lane = tid & 63;
  const int w = tid >> 6;
  const int q16 = lane & 15;
  const int g = lane >> 4;
  const size_t r0 = (size_t)blockIdx.x * 64;

  const int srow = tid >> 2;
  const int sc = (tid & 3) << 4;
  const float* xrow = x + (r0 + srow) * DD + sc;

  f32x4 acc[4][3];
#pragma unroll
  for (int mf = 0; mf < 4; ++mf)
#pragma unroll
    for (int nf = 0; nf < 3; ++nf) acc[mf][nf] = (f32x4){0.f, 0.f, 0.f, 0.f};

  const short* wp[3];
#pragma unroll
  for (int nf = 0; nf < 3; ++nf)
    wp[nf] = wt + (size_t)(w * 48 + nf * 16 + q16) * DD + g * 8;

  // prologue: x(0) -> xs[0], B(0) -> regs
  {
    const float4* xp = (const float4*)xrow;
    float4 a0 = xp[0], a1 = xp[1], a2 = xp[2], a3 = xp[3];
    bf16x8 s0, s1;
    pack16(a0, a1, a2, a3, s0, s1);
    *(bf16x8*)lds_swz(xs[0], srow, sc) = s0;
    *(bf16x8*)lds_swz(xs[0], srow, sc + 8) = s1;
  }
  bf16x8 bcur[3][2];
#pragma unroll
  for (int nf = 0; nf < 3; ++nf)
#pragma unroll
    for (int kf = 0; kf < 2; ++kf)
      bcur[nf][kf] = *(const bf16x8*)(wp[nf] + kf * 32);
  __syncthreads();

  int cur = 0;
  for (int ks = 0; ks < 16; ++ks) {
    float4 a0, a1, a2, a3;
    bf16x8 bnxt[3][2];
    if (ks < 15) {
      const int k1 = (ks + 1) << 6;
      const float4* xp = (const float4*)(xrow + k1);
      a0 = xp[0]; a1 = xp[1]; a2 = xp[2]; a3 = xp[3];
#pragma unroll
      for (int nf = 0; nf < 3; ++nf)
#pragma unroll
        for (int kf = 0; kf < 2; ++kf)
          bnxt[nf][kf] = *(const bf16x8*)(wp[nf] + k1 + kf * 32);
    }

    bf16x8 afr[4][2];
#pragma unroll
    for (int mf = 0; mf < 4; ++mf)
#pragma unroll
      for (int kf = 0; kf < 2; ++kf)
        afr[mf][kf] = *(bf16x8*)lds_swz(xs[cur], mf * 16 + q16, kf * 32 + g * 8);

#pragma unroll
    for (int mf = 0; mf < 4; ++mf)
#pragma unroll
      for (int nf = 0; nf < 3; ++nf)
#pragma unroll
        for (int kf = 0; kf < 2; ++kf)
          acc[mf][nf] = __builtin_amdgcn_mfma_f32_16x16x32_bf16(
              afr[mf][kf], bcur[nf][kf], acc[mf][nf], 0, 0, 0);

    if (ks < 15) {
      bf16x8 s0, s1;
      pack16(a0, a1, a2, a3, s0, s1);
      *(bf16x8*)lds_swz(xs[cur ^ 1], srow, sc) = s0;
      *(bf16x8*)lds_swz(xs[cur ^ 1], srow, sc + 8) = s1;
      __syncthreads();
      cur ^= 1;
#pragma unroll
      for (int nf = 0; nf < 3; ++nf)
#pragma unroll
        for (int kf = 0; kf < 2; ++kf) bcur[nf][kf] = bnxt[nf][kf];
    }
  }

  // epilogue: q/k row-major bf16; v transposed to vt [b][h][t]
#pragma unroll
  for (int nf = 0; nf < 3; ++nf) {
    const int n = w * 48 + nf * 16 + q16;
    const int mat = n >> 6;  // frag-uniform
    const int h = n & 63;
    if (mat < 2) {
      short* outp = mat ? ko : qo;
#pragma unroll
      for (int mf = 0; mf < 4; ++mf)
#pragma unroll
        for (int r = 0; r < 4; ++r)
          outp[(r0 + mf * 16 + g * 4 + r) * HH + h] = f2bf(acc[mf][nf][r]);
    } else {
      const int bb = (int)(r0 >> 11);
      const int tloc = (int)(r0 & 2047);
#pragma unroll
      for (int mf = 0; mf < 4; ++mf) {
        bf16x4 pk;
#pragma unroll
        for (int r = 0; r < 4; ++r) pk[r] = f2bf(acc[mf][nf][r]);
        *(bf16x4*)&vt[((size_t)bb * HH + h) * TT + tloc + mf * 16 + g * 4] = pk;
      }
    }
  }
}

// ---------------------------------------------------------------------------
// Flash attention, bf16 MFMA, pair-fused + double-buffered.
// Grid (16, B). Block = 512 thr = 8 waves: waves 0-3 own q-tile p, waves 4-7
// own q-tile 31-p (balanced causal pair), SHARING one K/V staging per chunk.
// Per chunk: issue next chunk's global loads -> compute (QK 8 mfma, online
// softmax, P via LDS bounce, PV 8 mfma) -> ds_write next -> one barrier.
// ---------------------------------------------------------------------------
__global__ __launch_bounds__(512) void attn_mfma(
    const short* __restrict__ q, const short* __restrict__ k,
    const short* __restrict__ vt, float* __restrict__ out) {
  __shared__ short klds[2][64 * 64];  // 16 KB
  __shared__ short vlds[2][64 * 64];  // 16 KB
  __shared__ short ps[8][16 * 72];    // 18 KB

  const int p = blockIdx.x;   // 0..15
  const int b = blockIdx.y;
  const int tid = threadIdx.x;
  const int lane = tid & 63;
  const int w = tid >> 6;     // 0..7
  const int grp = w >> 2;     // 0: tile p, 1: tile 31-p
  const int wl = w & 3;
  const int q16 = lane & 15;
  const int g = lane >> 4;

  const int qt = grp ? (31 - p) : p;
  const int qtB = 31 - p;     // heavy tile chunk count - 1 (qtB >= qt always)
  const int t0 = qt << 6;

  const size_t brow = (size_t)b * TT;
  const short* kg = k + brow * HH;
  const short* vtg = vt + (size_t)b * HH * TT;

  const int srow = tid >> 3;       // 0..63
  const int sca = (tid & 7) << 3;  // 0..56

  // stage both Q tiles (A->klds[0], B->klds[1]), pull per-wave frags
  *(bf16x8*)lds_swz(klds[0], srow, sca) =
      *(const bf16x8*)&q[(brow + (p << 6) + srow) * HH + sca];
  *(bf16x8*)lds_swz(klds[1], srow, sca) =
      *(const bf16x8*)&q[(brow + ((31 - p) << 6) + srow) * HH + sca];
  __syncthreads();
  bf16x8 qa[2];
#pragma unroll
  for (int kf = 0; kf < 2; ++kf)
    qa[kf] = *(bf16x8*)lds_swz(klds[grp], wl * 16 + q16, kf * 32 + g * 8);
  __syncthreads();

  // prologue: stage chunk 0
  bf16x8 kr = *(const bf16x8*)&kg[srow * HH + sca];
  bf16x8 vr = *(const bf16x8*)&vtg[srow * TT + sca];
  *(bf16x8*)lds_swz(klds[0], srow, sca) = kr;
  *(bf16x8*)lds_swz(vlds[0], srow, sca) = vr;
  __syncthreads();

  f32x4 po[4];
  float m[4], l[4];
#pragma unroll
  for (int nf = 0; nf < 4; ++nf) po[nf] = (f32x4){0.f, 0.f, 0.f, 0.f};
#pragma unroll
  for (int r = 0; r < 4; ++r) { m[r] = -INFINITY; l[r] = 0.f; }

  const int qrow = t0 + wl * 16 + g * 4;
  int cur = 0;

  for (int c = 0; c <= qtB; ++c) {
    // issue next chunk's global loads (hidden under compute)
    if (c < qtB) {
      const int s1 = (c + 1) << 6;
      kr = *(const bf16x8*)&kg[(s1 + srow) * HH + sca];
      vr = *(const bf16x8*)&vtg[srow * TT + s1 + sca];
    }

    if (c <= qt) {  // wave-group active?
      const int s0 = c << 6;
      // ---- S = Q . K^T ----
      f32x4 sfr[4];
#pragma unroll
      for (int nf = 0; nf < 4; ++nf) sfr[nf] = (f32x4){0.f, 0.f, 0.f, 0.f};
#pragma unroll
      for (int nf = 0; nf < 4; ++nf)
#pragma unroll
        for (int kf = 0; kf < 2; ++kf) {
          bf16x8 kb = *(bf16x8*)lds_swz(klds[cur], nf * 16 + q16, kf * 32 + g * 8);
          sfr[nf] = __builtin_amdgcn_mfma_f32_16x16x32_bf16(qa[kf], kb, sfr[nf], 0, 0, 0);
        }

      // ---- scale + causal mask (auto no-op for c<qt) ----
#pragma unroll
      for (int nf = 0; nf < 4; ++nf) {
        const int sg = s0 + nf * 16 + q16;
#pragma unroll
        for (int r = 0; r < 4; ++r) {
          float sv = sfr[nf][r] * 0.125f;
          sfr[nf][r] = (sg > qrow + r) ? -INFINITY : sv;
        }
      }

      // ---- online softmax (rows live across 16-lane groups) ----
      float mx[4], corr[4], psum[4];
#pragma unroll
      for (int r = 0; r < 4; ++r)
        mx[r] = fmaxf(fmaxf(sfr[0][r], sfr[1][r]), fmaxf(sfr[2][r], sfr[3][r]));
#pragma unroll
      for (int off = 8; off; off >>= 1)
#pragma unroll
        for (int r = 0; r < 4; ++r) mx[r] = fmaxf(mx[r], __shfl_xor(mx[r], off));
#pragma unroll
      for (int r = 0; r < 4; ++r) {
        const float mn = fmaxf(m[r], mx[r]);
        corr[r] = __expf(m[r] - mn);
        m[r] = mn;
      }
#pragma unroll
      for (int nf = 0; nf < 4; ++nf)
#pragma unroll
        for (int r = 0; r < 4; ++r) sfr[nf][r] = __expf(sfr[nf][r] - m[r]);
#pragma unroll
      for (int r = 0; r < 4; ++r)
        psum[r] = (sfr[0][r] + sfr[1][r]) + (sfr[2][r] + sfr[3][r]);
#pragma unroll
      for (int off = 8; off; off >>= 1)
#pragma unroll
        for (int r = 0; r < 4; ++r) psum[r] += __shfl_xor(psum[r], off);
#pragma unroll
      for (int r = 0; r < 4; ++r) l[r] = l[r] * corr[r] + psum[r];
#pragma unroll
      for (int nf = 0; nf < 4; ++nf)
#pragma unroll
        for (int r = 0; r < 4; ++r) po[nf][r] *= corr[r];

      // ---- P -> bf16 LDS [16q][72] ----
#pragma unroll
      for (int nf = 0; nf < 4; ++nf)
#pragma unroll
        for (int r = 0; r < 4; ++r)
          ps[w][(g * 4 + r) * 72 + nf * 16 + q16] = f2bf(sfr[nf][r]);

      // ---- O += P . V ----
      bf16x8 pa[2];
#pragma unroll
      for (int kf = 0; kf < 2; ++kf)
        pa[kf] = *(const bf16x8*)&ps[w][q16 * 72 + kf * 32 + g * 8];
#pragma unroll
      for (int nf = 0; nf < 4; ++nf)
#pragma unroll
        for (int kf = 0; kf < 2; ++kf) {
          bf16x8 vb = *(bf16x8*)lds_swz(vlds[cur], nf * 16 + q16, kf * 32 + g * 8);
          po[nf] = __builtin_amdgcn_mfma_f32_16x16x32_bf16(pa[kf], vb, po[nf], 0, 0, 0);
        }
    }

    // ---- write next chunk into other buffer, single barrier ----
    if (c < qtB) {
      *(bf16x8*)lds_swz(klds[cur ^ 1], srow, sca) = kr;
      *(bf16x8*)lds_swz(vlds[cur ^ 1], srow, sca) = vr;
      __syncthreads();
      cur ^= 1;
    }
  }

#pragma unroll
  for (int nf = 0; nf < 4; ++nf) {
    const int h = nf * 16 + q16;
#pragma unroll
    for (int r = 0; r < 4; ++r)
      out[(brow + qrow + r) * HH + h] = po[nf][r] / l[r];
  }
}

extern "C" void kernel_launch(void* const* d_in, const int* in_sizes, int n_in,
                              void* d_out, int out_size, void* d_ws, size_t ws_size,
                              hipStream_t stream) {
  const float* x  = (const float*)d_in[0];
  const float* Wq = (const float*)d_in[1];
  const float* Wk = (const float*)d_in[2];
  const float* Wv = (const float*)d_in[3];
  float* out = (float*)d_out;

  const size_t bth = (size_t)BB * TT * HH;  // 2,097,152
  short* qb  = (short*)d_ws;
  short* kb  = qb + bth;
  short* vtb = kb + bth;
  short* wtb = vtb + bth;  // 192*1024 bf16

  pack_wt<<<96, 256, 0, stream>>>(Wq, Wk, Wv, wtb);
  qkv_mfma<<<(BB * TT) / 64, 256, 0, stream>>>(x, wtb, qb, kb, vtb);
  attn_mfma<<<dim3(16, BB), 512, 0, stream>>>(qb, kb, vtb, out);
}

// Round 5
// 86.801 us; speedup vs baseline: 31.5672x; 1.0468x over previous
//
#include <hip/hip_runtime.h>
#include <math.h>

#define BB 16
#define TT 2048
#define DD 1024
#define HH 64
#define QK_SCALE 0.18033688011112042f  // 0.125 * log2(e)  (exp2-domain softmax)

typedef short bf16x8 __attribute__((ext_vector_type(8)));
typedef short bf16x4 __attribute__((ext_vector_type(4)));
typedef float f32x4 __attribute__((ext_vector_type(4)));

__device__ __forceinline__ short f2bf(float f) {  // RNE
  union { float f; unsigned u; } c; c.f = f;
  unsigned u = c.u + 0x7FFFu + ((c.u >> 16) & 1u);
  return (short)(u >> 16);
}
__device__ __forceinline__ short f2bf_up(float f) {  // round-half-up (P>=0)
  union { float f; unsigned u; } c; c.f = f;
  return (short)((c.u + 0x8000u) >> 16);
}

// 64-col bf16 tile (128B row stride): XOR-swizzle 16B units by row&7.
__device__ __forceinline__ void* lds_swz(void* base, int row, int col) {
  int byte = (row << 7) + (col << 1);
  byte ^= (row & 7) << 4;
  return (void*)((char*)base + byte);
}
// 128-col bf16 tile (256B row stride).
__device__ __forceinline__ void* lds_swz256(void* base, int row, int col) {
  int byte = (row << 8) + (col << 1);
  byte ^= (row & 7) << 4;
  return (void*)((char*)base + byte);
}

__device__ __forceinline__ void pack16(const float4& a0, const float4& a1,
                                       const float4& a2, const float4& a3,
                                       bf16x8& s0, bf16x8& s1) {
  s0[0] = f2bf(a0.x); s0[1] = f2bf(a0.y); s0[2] = f2bf(a0.z); s0[3] = f2bf(a0.w);
  s0[4] = f2bf(a1.x); s0[5] = f2bf(a1.y); s0[6] = f2bf(a1.z); s0[7] = f2bf(a1.w);
  s1[0] = f2bf(a2.x); s1[1] = f2bf(a2.y); s1[2] = f2bf(a2.z); s1[3] = f2bf(a2.w);
  s1[4] = f2bf(a3.x); s1[5] = f2bf(a3.y); s1[6] = f2bf(a3.z); s1[7] = f2bf(a3.w);
}

// ---------------------------------------------------------------------------
// Pack Wq|Wk|Wv (fp32 [D][H]) -> Wt bf16 [192][1024]  (n-major, k contiguous)
// ---------------------------------------------------------------------------
__global__ __launch_bounds__(256) void pack_wt(
    const float* __restrict__ Wq, const float* __restrict__ Wk,
    const float* __restrict__ Wv, short* __restrict__ wt) {
  const int idx = blockIdx.x * 256 + threadIdx.x;
  const int n = idx >> 7;
  const int k0 = (idx & 127) << 3;
  const float* W = (n < 64) ? Wq : (n < 128) ? Wk : Wv;
  const int h = n & 63;
  bf16x8 o;
#pragma unroll
  for (int j = 0; j < 8; ++j) o[j] = f2bf(W[(k0 + j) * HH + h]);
  *(bf16x8*)&wt[n * DD + k0] = o;
}

// ---------------------------------------------------------------------------
// QKV GEMM, double-buffered bf16 MFMA. Q output pre-scaled by QK_SCALE
// (softmax runs in exp2 domain). V written transposed to vt [b][h][t].
// ---------------------------------------------------------------------------
__global__ __launch_bounds__(256) void qkv_mfma(
    const float* __restrict__ x, const short* __restrict__ wt,
    short* __restrict__ qo, short* __restrict__ ko, short* __restrict__ vt) {
  __shared__ short xs[2][64 * 64];
  const int tid = threadIdx.x;
  const int lane = tid & 63;
  const int w = tid >> 6;
  const int q16 = lane & 15;
  const int g = lane >> 4;
  const size_t r0 = (size_t)blockIdx.x * 64;

  const int srow = tid >> 2;
  const int sc = (tid & 3) << 4;
  const float* xrow = x + (r0 + srow) * DD + sc;

  f32x4 acc[4][3];
#pragma unroll
  for (int mf = 0; mf < 4; ++mf)
#pragma unroll
    for (int nf = 0; nf < 3; ++nf) acc[mf][nf] = (f32x4){0.f, 0.f, 0.f, 0.f};

  const short* wp[3];
#pragma unroll
  for (int nf = 0; nf < 3; ++nf)
    wp[nf] = wt + (size_t)(w * 48 + nf * 16 + q16) * DD + g * 8;

  {
    const float4* xp = (const float4*)xrow;
    float4 a0 = xp[0], a1 = xp[1], a2 = xp[2], a3 = xp[3];
    bf16x8 s0, s1;
    pack16(a0, a1, a2, a3, s0, s1);
    *(bf16x8*)lds_swz(xs[0], srow, sc) = s0;
    *(bf16x8*)lds_swz(xs[0], srow, sc + 8) = s1;
  }
  bf16x8 bcur[3][2];
#pragma unroll
  for (int nf = 0; nf < 3; ++nf)
#pragma unroll
    for (int kf = 0; kf < 2; ++kf)
      bcur[nf][kf] = *(const bf16x8*)(wp[nf] + kf * 32);
  __syncthreads();

  int cur = 0;
  for (int ks = 0; ks < 16; ++ks) {
    float4 a0, a1, a2, a3;
    bf16x8 bnxt[3][2];
    if (ks < 15) {
      const int k1 = (ks + 1) << 6;
      const float4* xp = (const float4*)(xrow + k1);
      a0 = xp[0]; a1 = xp[1]; a2 = xp[2]; a3 = xp[3];
#pragma unroll
      for (int nf = 0; nf < 3; ++nf)
#pragma unroll
        for (int kf = 0; kf < 2; ++kf)
          bnxt[nf][kf] = *(const bf16x8*)(wp[nf] + k1 + kf * 32);
    }

    bf16x8 afr[4][2];
#pragma unroll
    for (int mf = 0; mf < 4; ++mf)
#pragma unroll
      for (int kf = 0; kf < 2; ++kf)
        afr[mf][kf] = *(bf16x8*)lds_swz(xs[cur], mf * 16 + q16, kf * 32 + g * 8);

#pragma unroll
    for (int mf = 0; mf < 4; ++mf)
#pragma unroll
      for (int nf = 0; nf < 3; ++nf)
#pragma unroll
        for (int kf = 0; kf < 2; ++kf)
          acc[mf][nf] = __builtin_amdgcn_mfma_f32_16x16x32_bf16(
              afr[mf][kf], bcur[nf][kf], acc[mf][nf], 0, 0, 0);

    if (ks < 15) {
      bf16x8 s0, s1;
      pack16(a0, a1, a2, a3, s0, s1);
      *(bf16x8*)lds_swz(xs[cur ^ 1], srow, sc) = s0;
      *(bf16x8*)lds_swz(xs[cur ^ 1], srow, sc + 8) = s1;
      __syncthreads();
      cur ^= 1;
#pragma unroll
      for (int nf = 0; nf < 3; ++nf)
#pragma unroll
        for (int kf = 0; kf < 2; ++kf) bcur[nf][kf] = bnxt[nf][kf];
    }
  }

#pragma unroll
  for (int nf = 0; nf < 3; ++nf) {
    const int n = w * 48 + nf * 16 + q16;
    const int mat = n >> 6;  // frag-uniform
    const int h = n & 63;
    if (mat < 2) {
      short* outp = mat ? ko : qo;
      const float fac = mat ? 1.0f : QK_SCALE;
#pragma unroll
      for (int mf = 0; mf < 4; ++mf)
#pragma unroll
        for (int r = 0; r < 4; ++r)
          outp[(r0 + mf * 16 + g * 4 + r) * HH + h] = f2bf(acc[mf][nf][r] * fac);
    } else {
      const int bb = (int)(r0 >> 11);
      const int tloc = (int)(r0 & 2047);
#pragma unroll
      for (int mf = 0; mf < 4; ++mf) {
        bf16x4 pk;
#pragma unroll
        for (int r = 0; r < 4; ++r) pk[r] = f2bf(acc[mf][nf][r]);
        *(bf16x4*)&vt[((size_t)bb * HH + h) * TT + tloc + mf * 16 + g * 4] = pk;
      }
    }
  }
}

// ---------------------------------------------------------------------------
// Flash attention, bf16 MFMA. Pair-fused (tiles p & 31-p share staging),
// KVBLK=128, double-buffered, exp2-domain softmax with defer-max (THR=8),
// l accumulated via ones-MFMA. One barrier per 128-key chunk.
// ---------------------------------------------------------------------------
__global__ __launch_bounds__(512) void attn_mfma(
    const short* __restrict__ q, const short* __restrict__ k,
    const short* __restrict__ vt, float* __restrict__ out) {
  __shared__ short klds[2][128 * 64];   // 32 KB, K [key][d] (also Q staging)
  __shared__ short vlds[2][64 * 128];   // 32 KB, V^T [h][key]
  __shared__ short ps[8][16 * 136];     // 34 KB, per-wave P [16q][136]

  const int p = blockIdx.x;   // 0..15
  const int b = blockIdx.y;
  const int tid = threadIdx.x;
  const int lane = tid & 63;
  const int w = tid >> 6;     // 0..7
  const int grp = w >> 2;     // 0: tile p, 1: tile 31-p
  const int wl = w & 3;
  const int q16 = lane & 15;
  const int g = lane >> 4;

  const int qt = grp ? (31 - p) : p;
  const int t0 = qt << 6;
  const int NC = (33 - p) >> 1;            // 128-key chunks for heavy tile
  const int cmax = (qt * 64 + 63) >> 7;    // last active chunk for this group
  const int qrow = t0 + wl * 16 + g * 4;

  const size_t brow = (size_t)b * TT;
  const short* kg = k + brow * HH;
  const short* vtg = vt + (size_t)b * HH * TT;

  const int srow2 = tid >> 2;        // 0..127 (K rows / Q staging rows)
  const int scq = (tid & 3) << 4;    // 0,16,32,48
  const int vrow = tid >> 3;         // 0..63  (V^T rows)
  const int vcol = (tid & 7) << 4;   // 0..112

  // issue chunk-0 K/V loads first; latency hides under Q staging
  bf16x8 kr0 = *(const bf16x8*)&kg[srow2 * HH + scq];
  bf16x8 kr1 = *(const bf16x8*)&kg[srow2 * HH + scq + 8];
  bf16x8 vr0 = *(const bf16x8*)&vtg[vrow * TT + vcol];
  bf16x8 vr1 = *(const bf16x8*)&vtg[vrow * TT + vcol + 8];

  // stage both Q tiles into klds[0] (rows 0..63: tile p, 64..127: tile 31-p)
  {
    const int qtrow = (srow2 < 64) ? ((p << 6) + srow2)
                                   : (((31 - p) << 6) + (srow2 - 64));
    const short* qsrc = q + (brow + qtrow) * HH;
    *(bf16x8*)lds_swz(klds[0], srow2, scq) = *(const bf16x8*)&qsrc[scq];
    *(bf16x8*)lds_swz(klds[0], srow2, scq + 8) = *(const bf16x8*)&qsrc[scq + 8];
  }
  __syncthreads();
  bf16x8 qa[2];
#pragma unroll
  for (int kf = 0; kf < 2; ++kf)
    qa[kf] = *(bf16x8*)lds_swz(klds[0], grp * 64 + wl * 16 + q16, kf * 32 + g * 8);
  __syncthreads();

  // write chunk 0
  *(bf16x8*)lds_swz(klds[0], srow2, scq) = kr0;
  *(bf16x8*)lds_swz(klds[0], srow2, scq + 8) = kr1;
  *(bf16x8*)lds_swz256(vlds[0], vrow, vcol) = vr0;
  *(bf16x8*)lds_swz256(vlds[0], vrow, vcol + 8) = vr1;
  __syncthreads();

  f32x4 po[4];
  f32x4 lacc = (f32x4){0.f, 0.f, 0.f, 0.f};
  float m[4];
#pragma unroll
  for (int nf = 0; nf < 4; ++nf) po[nf] = (f32x4){0.f, 0.f, 0.f, 0.f};
#pragma unroll
  for (int r = 0; r < 4; ++r) m[r] = -INFINITY;

  const bf16x8 ones = {0x3F80, 0x3F80, 0x3F80, 0x3F80,
                       0x3F80, 0x3F80, 0x3F80, 0x3F80};
  int cur = 0;

  for (int c = 0; c < NC; ++c) {
    const bool notlast = (c + 1 < NC);
    if (notlast) {  // T14: issue next chunk's globals before compute
      const int s1 = (c + 1) << 7;
      kr0 = *(const bf16x8*)&kg[(s1 + srow2) * HH + scq];
      kr1 = *(const bf16x8*)&kg[(s1 + srow2) * HH + scq + 8];
      vr0 = *(const bf16x8*)&vtg[vrow * TT + s1 + vcol];
      vr1 = *(const bf16x8*)&vtg[vrow * TT + s1 + vcol + 8];
    }

    if (c <= cmax) {
      // ---- S = Q . K^T (exp2-domain: Q pre-scaled) ----
      f32x4 sfr[8];
#pragma unroll
      for (int nf = 0; nf < 8; ++nf) sfr[nf] = (f32x4){0.f, 0.f, 0.f, 0.f};
#pragma unroll
      for (int nf = 0; nf < 8; ++nf)
#pragma unroll
        for (int kf = 0; kf < 2; ++kf) {
          bf16x8 kb = *(bf16x8*)lds_swz(klds[cur], nf * 16 + q16, kf * 32 + g * 8);
          sfr[nf] = __builtin_amdgcn_mfma_f32_16x16x32_bf16(qa[kf], kb, sfr[nf], 0, 0, 0);
        }

      // ---- causal mask: diagonal chunk only ----
      if (c == cmax) {
        const int sbase = (c << 7) + q16;
#pragma unroll
        for (int nf = 0; nf < 8; ++nf)
#pragma unroll
          for (int r = 0; r < 4; ++r)
            if (sbase + nf * 16 > qrow + r) sfr[nf][r] = -INFINITY;
      }

      // ---- row max (over 8 frags, then 16 lanes) ----
      float pm[4];
#pragma unroll
      for (int r = 0; r < 4; ++r) {
        float a = fmaxf(fmaxf(sfr[0][r], sfr[1][r]), fmaxf(sfr[2][r], sfr[3][r]));
        float bx = fmaxf(fmaxf(sfr[4][r], sfr[5][r]), fmaxf(sfr[6][r], sfr[7][r]));
        pm[r] = fmaxf(a, bx);
      }
#pragma unroll
      for (int off = 8; off; off >>= 1)
#pragma unroll
        for (int r = 0; r < 4; ++r) pm[r] = fmaxf(pm[r], __shfl_xor(pm[r], off));

      // ---- defer-max (T13): rescale only if growth > 8 (log2 units) ----
      float growth = fmaxf(fmaxf(pm[0] - m[0], pm[1] - m[1]),
                           fmaxf(pm[2] - m[2], pm[3] - m[3]));
      if (__any(growth > 8.f)) {
#pragma unroll
        for (int r = 0; r < 4; ++r) {
          const float mn = fmaxf(m[r], pm[r]);
          const float corr = exp2f(m[r] - mn);
          m[r] = mn;
          lacc[r] *= corr;
#pragma unroll
          for (int nf = 0; nf < 4; ++nf) po[nf][r] *= corr;
        }
      }

      // ---- P = exp2(S - m) -> bf16 -> per-wave LDS [16q][136] ----
#pragma unroll
      for (int nf = 0; nf < 8; ++nf)
#pragma unroll
        for (int r = 0; r < 4; ++r)
          ps[w][(g * 4 + r) * 136 + nf * 16 + q16] = f2bf_up(exp2f(sfr[nf][r] - m[r]));

      // ---- O += P.V ; l += P.1 (ones-MFMA) ----
      bf16x8 pa[4];
#pragma unroll
      for (int kf = 0; kf < 4; ++kf)
        pa[kf] = *(const bf16x8*)&ps[w][q16 * 136 + kf * 32 + g * 8];
#pragma unroll
      for (int nf = 0; nf < 4; ++nf)
#pragma unroll
        for (int kf = 0; kf < 4; ++kf) {
          bf16x8 vb = *(bf16x8*)lds_swz256(vlds[cur], nf * 16 + q16, kf * 32 + g * 8);
          po[nf] = __builtin_amdgcn_mfma_f32_16x16x32_bf16(pa[kf], vb, po[nf], 0, 0, 0);
        }
#pragma unroll
      for (int kf = 0; kf < 4; ++kf)
        lacc = __builtin_amdgcn_mfma_f32_16x16x32_bf16(pa[kf], ones, lacc, 0, 0, 0);
    }

    if (notlast) {
      *(bf16x8*)lds_swz(klds[cur ^ 1], srow2, scq) = kr0;
      *(bf16x8*)lds_swz(klds[cur ^ 1], srow2, scq + 8) = kr1;
      *(bf16x8*)lds_swz256(vlds[cur ^ 1], vrow, vcol) = vr0;
      *(bf16x8*)lds_swz256(vlds[cur ^ 1], vrow, vcol + 8) = vr1;
      __syncthreads();
      cur ^= 1;
    }
  }

#pragma unroll
  for (int nf = 0; nf < 4; ++nf) {
    const int h = nf * 16 + q16;
#pragma unroll
    for (int r = 0; r < 4; ++r)
      out[(brow + qrow + r) * HH + h] = po[nf][r] / lacc[r];
  }
}

extern "C" void kernel_launch(void* const* d_in, const int* in_sizes, int n_in,
                              void* d_out, int out_size, void* d_ws, size_t ws_size,
                              hipStream_t stream) {
  const float* x  = (const float*)d_in[0];
  const float* Wq = (const float*)d_in[1];
  const float* Wk = (const float*)d_in[2];
  const float* Wv = (const float*)d_in[3];
  float* out = (float*)d_out;

  const size_t bth = (size_t)BB * TT * HH;  // 2,097,152
  short* qb  = (short*)d_ws;
  short* kb  = qb + bth;
  short* vtb = kb + bth;
  short* wtb = vtb + bth;  // 192*1024 bf16

  pack_wt<<<96, 256, 0, stream>>>(Wq, Wk, Wv, wtb);
  qkv_mfma<<<(BB * TT) / 64, 256, 0, stream>>>(x, wtb, qb, kb, vtb);
  attn_mfma<<<dim3(16, BB), 512, 0, stream>>>(qb, kb, vtb, out);
}